// Round 22
// baseline (74.812 us; speedup 1.0000x reference)
//
#include <hip/hip_runtime.h>
#include <hip/hip_bf16.h>
#include <hip/hip_cooperative_groups.h>

namespace cg = cooperative_groups;

#define IN_F 8192
#define OUT_F 8192
#define BATCH 64
#define KSPLIT 8

typedef __attribute__((ext_vector_type(8))) _Float16 f16x8_t;  // 8 f16 (4 VGPRs)
typedef __attribute__((ext_vector_type(2))) _Float16 f16x2_t;  // packed pair
typedef __attribute__((ext_vector_type(8))) ushort   u16x8_t;  // 16B store unit
typedef __attribute__((ext_vector_type(4))) ushort   u16x4_t;  // 8B load unit
typedef __attribute__((ext_vector_type(4))) float    f32x4_t;  // MFMA accumulator

// ---------------------------------------------------------------------------
// R22 = R16 (25.3us anchor) fused into ONE cooperative kernel:
//   phase 1: x fp32 -> f16 LDS (k-permuted, XOR swz) + f16-MFMA GEMM with
//            int4->f16 magic dequant + bf16 fragment-major partial store
//            (byte-identical K-loop to R16).
//   grid.sync()  -- single device-scope barrier (256 blocks, 1/CU, all
//                   co-resident by construction; NOT R11's per-block
//                   fence/ticket storm).
//   phase 2: inlined reduce: 131072 threads x 4 elems, 8B coalesced
//            partial reads (L2/HBM-warm), + bias, one store per element.
// Kills one dispatch ramp + one full inter-dispatch drain (~9us tail was
// reduce+boundary vs ~1.6us of actual reduce traffic).
// ---------------------------------------------------------------------------
__global__ void __launch_bounds__(512, 2)
wol_fused(const float*  __restrict__ x,
          const int*    __restrict__ qw,
          const int*    __restrict__ qz,
          const float*  __restrict__ sc,
          ushort*       __restrict__ part,
          const float*  __restrict__ bias,
          float*        __restrict__ out) {
    const int nt   = blockIdx.x & 31;
    const int ks   = blockIdx.x >> 5;           // 0..7
    const int wid  = threadIdx.x >> 6;
    const int lane = threadIdx.x & 63;
    const int ln   = lane & 15;
    const int kb   = lane >> 4;                 // k-subblock 0..3
    const int colbase = nt * 256 + wid * 32;    // wave's 32 columns
    const int k0      = ks * 1024;              // block K range (8 groups)
    const int gbase   = k0 >> 7;
    const int qrowb   = k0 >> 3;                // 128 qrows per block

    // ---- group-0 prefetch (in flight across LDS staging + barrier) ----
    unsigned qc[4][2]; float svc[2]; unsigned zwc[2];
#pragma unroll
    for (int kt = 0; kt < 4; ++kt)
#pragma unroll
        for (int nj = 0; nj < 2; ++nj)
            qc[kt][nj] = (unsigned)qw[(size_t)(qrowb + kt * 4 + kb) * OUT_F +
                                      colbase + nj * 16 + ln];
#pragma unroll
    for (int nj = 0; nj < 2; ++nj) {
        const int c = colbase + nj * 16 + ln;
        svc[nj] = sc[gbase * OUT_F + c];
        zwc[nj] = (unsigned)qz[gbase * (OUT_F / 8) + (c >> 3)];
    }
    __builtin_amdgcn_sched_barrier(0);          // pin group-0 loads here

    // ---- fused staging: x fp32 -> f16, k-permuted, swizzled LDS (128KB) ----
    __shared__ ushort lds_x[128 * 64 * 8];
    {
        const int perm[8] = {0, 4, 1, 5, 2, 6, 3, 7};   // frag j -> source k
#pragma unroll
        for (int i = 0; i < 16; ++i) {
            const int idx = i * 512 + (int)threadIdx.x;  // 8192 frags
            const int row = idx >> 7;                    // 0..63
            const int k8l = idx & 127;                   // 0..127
            const float4* sp = (const float4*)&x[(size_t)row * IN_F + k0 + k8l * 8];
            const float4 a = sp[0], b = sp[1];
            const float f[8] = {a.x, a.y, a.z, a.w, b.x, b.y, b.z, b.w};
            union { ushort u[8]; u16x8_t v; } o;
#pragma unroll
            for (int j = 0; j < 8; ++j) {
                const _Float16 h = (_Float16)f[perm[j]];
                o.u[j] = *(const ushort*)&h;
            }
            unsigned byteoff = (unsigned)(row * 2048 + k8l * 16);
            byteoff ^= (unsigned)((row & 7) << 4);       // T2 XOR swizzle
            *(u16x8_t*)((char*)lds_x + byteoff) = o.v;
        }
    }
    __syncthreads();

    const unsigned xorv = (unsigned)((ln & 7) << 4);     // af-read swizzle

    f32x4_t acc[4][2];
#pragma unroll
    for (int mi = 0; mi < 4; ++mi)
#pragma unroll
        for (int nj = 0; nj < 2; ++nj) acc[mi][nj] = (f32x4_t)0.0f;

#pragma unroll 1
    for (int g = 0; g < 8; ++g) {               // 8 quant groups of 128 K
        // ---- prefetch group g+1 BEFORE computing group g, pinned ----
        unsigned qn[4][2]; float svn[2]; unsigned zwn[2];
        if (g < 7) {
            const int qrow1 = qrowb + (g + 1) * 16;
#pragma unroll
            for (int kt = 0; kt < 4; ++kt)
#pragma unroll
                for (int nj = 0; nj < 2; ++nj)
                    qn[kt][nj] = (unsigned)qw[(size_t)(qrow1 + kt * 4 + kb) * OUT_F +
                                              colbase + nj * 16 + ln];
#pragma unroll
            for (int nj = 0; nj < 2; ++nj) {
                const int c = colbase + nj * 16 + ln;
                svn[nj] = sc[(gbase + g + 1) * OUT_F + c];
                zwn[nj] = (unsigned)qz[(gbase + g + 1) * (OUT_F / 8) + (c >> 3)];
            }
            __builtin_amdgcn_sched_barrier(0);  // loads stay ABOVE the compute
        }

        // per-group packed f16 constants: c2 = -(1024+zp) (exact), s2 = s
        f16x2_t c2[2], s2[2];
#pragma unroll
        for (int nj = 0; nj < 2; ++nj) {
            const unsigned zp = ((zwc[nj] >> ((ln & 7) * 4)) + 1u) & 15u;  // zp-1 stored
            const _Float16 hc = (_Float16)(-(float)(1024u + zp));
            const _Float16 hs = (_Float16)svc[nj];
            c2[nj][0] = hc; c2[nj][1] = hc;
            s2[nj][0] = hs; s2[nj][1] = hs;
        }

#pragma unroll
        for (int kt = 0; kt < 4; ++kt) {        // 4 K-steps of 32
            const unsigned kbyte = (unsigned)(g * 256 + kt * 64 + kb * 16) ^ xorv;
            f16x8_t af[4];
#pragma unroll
            for (int mi = 0; mi < 4; ++mi)
                af[mi] = *(const f16x8_t*)((const char*)lds_x +
                            (unsigned)((mi * 16 + ln) * 2048) + kbyte);
#pragma unroll
            for (int nj = 0; nj < 2; ++nj) {
                const unsigned qv = qc[kt][nj];
                // int4 -> f16 magic unpack: pairs (n_i, n_{i+4}) at +1024
                const unsigned r0 = ( qv        & 0x000F000Fu) | 0x64006400u;
                const unsigned r1 = ((qv >> 4)  & 0x000F000Fu) | 0x64006400u;
                const unsigned r2 = ((qv >> 8)  & 0x000F000Fu) | 0x64006400u;
                const unsigned r3 = ((qv >> 12) & 0x000F000Fu) | 0x64006400u;
                union { unsigned u[4]; f16x8_t v; } bu;
                union { unsigned u; f16x2_t h; } t0, t1, t2, t3;
                t0.u = r0; t1.u = r1; t2.u = r2; t3.u = r3;
                f16x2_t w0 = (t0.h + c2[nj]) * s2[nj];   // pk_add exact, pk_mul
                f16x2_t w1 = (t1.h + c2[nj]) * s2[nj];
                f16x2_t w2 = (t2.h + c2[nj]) * s2[nj];
                f16x2_t w3 = (t3.h + c2[nj]) * s2[nj];
                bu.u[0] = *(const unsigned*)&w0;
                bu.u[1] = *(const unsigned*)&w1;
                bu.u[2] = *(const unsigned*)&w2;
                bu.u[3] = *(const unsigned*)&w3;
#pragma unroll
                for (int mi = 0; mi < 4; ++mi)
                    acc[mi][nj] = __builtin_amdgcn_mfma_f32_16x16x32_f16(
                        af[mi], bu.v, acc[mi][nj], 0, 0, 0);
            }
        }

        if (g < 7) {                            // rotate prefetch buffers
#pragma unroll
            for (int kt = 0; kt < 4; ++kt)
#pragma unroll
                for (int nj = 0; nj < 2; ++nj) qc[kt][nj] = qn[kt][nj];
#pragma unroll
            for (int nj = 0; nj < 2; ++nj) { svc[nj] = svn[nj]; zwc[nj] = zwn[nj]; }
        }
    }

    // ---- store bf16 fragment-major partials, one 64B store/thread ----
    union { ushort u[32]; u16x8_t v8[4]; } ob;
#pragma unroll
    for (int mi = 0; mi < 4; ++mi)
#pragma unroll
        for (int nj = 0; nj < 2; ++nj)
#pragma unroll
            for (int j = 0; j < 4; ++j) {
                __hip_bfloat16 h = __float2bfloat16(acc[mi][nj][j]);
                ob.u[(mi * 2 + nj) * 4 + j] = *reinterpret_cast<ushort*>(&h);
            }
    u16x8_t* pb = (u16x8_t*)part + ((size_t)(ks * 32 + nt) * 512 + threadIdx.x) * 4;
#pragma unroll
    for (int i = 0; i < 4; ++i) pb[i] = ob.v8[i];

    // ---- grid-wide barrier: all partials visible ----
    cg::this_grid().sync();

    // ---- phase 2: reduce 8 K-splits + bias -> out (131072 thr x 4 elems) --
    const int u    = blockIdx.x * 512 + (int)threadIdx.x;
    const int v4   = u & 7;              // which ushort4 of the thread's 64B
    const int tidA = (u >> 3) & 511;     // stage-A thread id
    const int ntR  = u >> 12;            // stage-A N-tile 0..31

    float s4[4] = {0.0f, 0.0f, 0.0f, 0.0f};
#pragma unroll
    for (int k2 = 0; k2 < KSPLIT; ++k2) {
        const u16x4_t p = *((const u16x4_t*)part +
                            (((size_t)(k2 * 32 + ntR) * 512 + tidA) * 8 + v4));
#pragma unroll
        for (int e = 0; e < 4; ++e) {
            union { unsigned b; float f; } cv;
            cv.b = ((unsigned)(ushort)p[e]) << 16;   // bf16 -> f32 exact
            s4[e] += cv.f;
        }
    }

    const int widR = tidA >> 6, laneR = tidA & 63;
    const int lnR = laneR & 15, kbR = laneR >> 4;
#pragma unroll
    for (int e = 0; e < 4; ++e) {
        const int idx = v4 * 4 + e;                  // (mi*2+nj)*4 + j
        const int mi = idx >> 3, nj = (idx >> 2) & 1, j = idx & 3;
        const int row = mi * 16 + kbR * 4 + j;
        const int col = ntR * 256 + widR * 32 + nj * 16 + lnR;
        out[(size_t)row * OUT_F + col] = s4[e] + bias[col];
    }
}

extern "C" void kernel_launch(void* const* d_in, const int* in_sizes, int n_in,
                              void* d_out, int out_size, void* d_ws, size_t ws_size,
                              hipStream_t stream) {
    const float* x    = (const float*)d_in[0];
    const int*   qw   = (const int*)d_in[1];
    const int*   qz   = (const int*)d_in[2];
    const float* sc   = (const float*)d_in[3];
    const float* bias = (const float*)d_in[4];
    float* out = (float*)d_out;

    ushort* prt = (ushort*)d_ws;                 // 8 MiB bf16 partials

    (void)in_sizes; (void)n_in; (void)ws_size; (void)out_size;

    void* args[] = {(void*)&x, (void*)&qw, (void*)&qz, (void*)&sc,
                    (void*)&prt, (void*)&bias, (void*)&out};
    hipLaunchCooperativeKernel((void*)wol_fused, dim3(256), dim3(512),
                               args, 0, stream);
}

// Round 24
// 25.341 us; speedup vs baseline: 2.9522x; 2.9522x over previous
//
#include <hip/hip_runtime.h>
#include <hip/hip_bf16.h>

#define IN_F 8192
#define OUT_F 8192
#define BATCH 64
#define KSPLIT 8

typedef __attribute__((ext_vector_type(8))) _Float16 f16x8_t;  // 8 f16 (4 VGPRs)
typedef __attribute__((ext_vector_type(2))) _Float16 f16x2_t;  // packed pair
typedef __attribute__((ext_vector_type(2))) __fp16   fp16x2v;  // cvt_pkrtz result
typedef __attribute__((ext_vector_type(8))) ushort   u16x8_t;  // 16B unit
typedef __attribute__((ext_vector_type(4))) ushort   u16x4_t;  // 8B unit
typedef __attribute__((ext_vector_type(4))) float    f32x4_t;  // MFMA accumulator

// ---------------------------------------------------------------------------
// R24 = R23 with the cvt_pkrtz type fixed (__fp16 vector, same bits):
//  (1) staging: x fp32->f16 via v_cvt_pkrtz (1 op / 2 elems); pair order
//      (a.x,b.x)(a.y,b.y)(a.z,b.z)(a.w,b.w) IS the k-permuted fragment
//      order [0,4,1,5,2,6,3,7] -> permute free. (staging ~6.6us of the
//      18.1us mfma dispatch)
//  (2) reduce: 512 blocks x 256 thr, u16x4 8B loads, 4 outputs/thread
//      (was 256 blocks = 1 wave/SIMD, ~7.2us for ~10MB = TLP-starved).
// K-loop byte-identical to R16: int4->f16 magic dequant + 16x16x32 f16
// MFMA, XOR-swizzled LDS, 1-deep pinned prefetch.
// ---------------------------------------------------------------------------
__global__ void __launch_bounds__(512, 4)
wol_mfma(const float*  __restrict__ x,
         const int*    __restrict__ qw,
         const int*    __restrict__ qz,
         const float*  __restrict__ sc,
         ushort*       __restrict__ part) {
    const int nt   = blockIdx.x & 31;
    const int ks   = blockIdx.x >> 5;           // 0..7
    const int wid  = threadIdx.x >> 6;
    const int lane = threadIdx.x & 63;
    const int ln   = lane & 15;
    const int kb   = lane >> 4;                 // k-subblock 0..3
    const int colbase = nt * 256 + wid * 32;    // wave's 32 columns
    const int k0      = ks * 1024;              // block K range (8 groups)
    const int gbase   = k0 >> 7;
    const int qrowb   = k0 >> 3;                // 128 qrows per block

    // ---- group-0 prefetch (in flight across LDS staging + barrier) ----
    unsigned qc[4][2]; float svc[2]; unsigned zwc[2];
#pragma unroll
    for (int kt = 0; kt < 4; ++kt)
#pragma unroll
        for (int nj = 0; nj < 2; ++nj)
            qc[kt][nj] = (unsigned)qw[(size_t)(qrowb + kt * 4 + kb) * OUT_F +
                                      colbase + nj * 16 + ln];
#pragma unroll
    for (int nj = 0; nj < 2; ++nj) {
        const int c = colbase + nj * 16 + ln;
        svc[nj] = sc[gbase * OUT_F + c];
        zwc[nj] = (unsigned)qz[gbase * (OUT_F / 8) + (c >> 3)];
    }
    __builtin_amdgcn_sched_barrier(0);          // pin group-0 loads here

    // ---- staging: x fp32 -> f16 via cvt_pkrtz, k-permuted, swizzled ----
    __shared__ ushort lds_x[128 * 64 * 8];      // 128 KB
    {
#pragma unroll
        for (int i = 0; i < 16; ++i) {
            const int idx = i * 512 + (int)threadIdx.x;  // 8192 frags
            const int row = idx >> 7;                    // 0..63
            const int k8l = idx & 127;                   // 0..127
            const float4* sp = (const float4*)&x[(size_t)row * IN_F + k0 + k8l * 8];
            const float4 a = sp[0], b = sp[1];
            // fragment order [0,4,1,5,2,6,3,7] == pairs (a.x,b.x)(a.y,b.y)...
            union { fp16x2v h[4]; u16x8_t v; } o;
            o.h[0] = __builtin_amdgcn_cvt_pkrtz(a.x, b.x);
            o.h[1] = __builtin_amdgcn_cvt_pkrtz(a.y, b.y);
            o.h[2] = __builtin_amdgcn_cvt_pkrtz(a.z, b.z);
            o.h[3] = __builtin_amdgcn_cvt_pkrtz(a.w, b.w);
            unsigned byteoff = (unsigned)(row * 2048 + k8l * 16);
            byteoff ^= (unsigned)((row & 7) << 4);       // T2 XOR swizzle
            *(u16x8_t*)((char*)lds_x + byteoff) = o.v;
        }
    }
    __syncthreads();

    const unsigned xorv = (unsigned)((ln & 7) << 4);     // af-read swizzle

    f32x4_t acc[4][2];
#pragma unroll
    for (int mi = 0; mi < 4; ++mi)
#pragma unroll
        for (int nj = 0; nj < 2; ++nj) acc[mi][nj] = (f32x4_t)0.0f;

#pragma unroll 1
    for (int g = 0; g < 8; ++g) {               // 8 quant groups of 128 K
        // ---- prefetch group g+1 BEFORE computing group g, pinned ----
        unsigned qn[4][2]; float svn[2]; unsigned zwn[2];
        if (g < 7) {
            const int qrow1 = qrowb + (g + 1) * 16;
#pragma unroll
            for (int kt = 0; kt < 4; ++kt)
#pragma unroll
                for (int nj = 0; nj < 2; ++nj)
                    qn[kt][nj] = (unsigned)qw[(size_t)(qrow1 + kt * 4 + kb) * OUT_F +
                                              colbase + nj * 16 + ln];
#pragma unroll
            for (int nj = 0; nj < 2; ++nj) {
                const int c = colbase + nj * 16 + ln;
                svn[nj] = sc[(gbase + g + 1) * OUT_F + c];
                zwn[nj] = (unsigned)qz[(gbase + g + 1) * (OUT_F / 8) + (c >> 3)];
            }
            __builtin_amdgcn_sched_barrier(0);  // loads stay ABOVE the compute
        }

        // per-group packed f16 constants: c2 = -(1024+zp) (exact), s2 = s
        f16x2_t c2[2], s2[2];
#pragma unroll
        for (int nj = 0; nj < 2; ++nj) {
            const unsigned zp = ((zwc[nj] >> ((ln & 7) * 4)) + 1u) & 15u;  // zp-1 stored
            const _Float16 hc = (_Float16)(-(float)(1024u + zp));
            const _Float16 hs = (_Float16)svc[nj];
            c2[nj][0] = hc; c2[nj][1] = hc;
            s2[nj][0] = hs; s2[nj][1] = hs;
        }

#pragma unroll
        for (int kt = 0; kt < 4; ++kt) {        // 4 K-steps of 32
            const unsigned kbyte = (unsigned)(g * 256 + kt * 64 + kb * 16) ^ xorv;
            f16x8_t af[4];
#pragma unroll
            for (int mi = 0; mi < 4; ++mi)
                af[mi] = *(const f16x8_t*)((const char*)lds_x +
                            (unsigned)((mi * 16 + ln) * 2048) + kbyte);
#pragma unroll
            for (int nj = 0; nj < 2; ++nj) {
                const unsigned qv = qc[kt][nj];
                // int4 -> f16 magic unpack: pairs (n_i, n_{i+4}) at +1024
                const unsigned r0 = ( qv        & 0x000F000Fu) | 0x64006400u;
                const unsigned r1 = ((qv >> 4)  & 0x000F000Fu) | 0x64006400u;
                const unsigned r2 = ((qv >> 8)  & 0x000F000Fu) | 0x64006400u;
                const unsigned r3 = ((qv >> 12) & 0x000F000Fu) | 0x64006400u;
                union { unsigned u[4]; f16x8_t v; } bu;
                union { unsigned u; f16x2_t h; } t0, t1, t2, t3;
                t0.u = r0; t1.u = r1; t2.u = r2; t3.u = r3;
                f16x2_t w0 = (t0.h + c2[nj]) * s2[nj];   // pk_add exact, pk_mul
                f16x2_t w1 = (t1.h + c2[nj]) * s2[nj];
                f16x2_t w2 = (t2.h + c2[nj]) * s2[nj];
                f16x2_t w3 = (t3.h + c2[nj]) * s2[nj];
                bu.u[0] = *(const unsigned*)&w0;
                bu.u[1] = *(const unsigned*)&w1;
                bu.u[2] = *(const unsigned*)&w2;
                bu.u[3] = *(const unsigned*)&w3;
#pragma unroll
                for (int mi = 0; mi < 4; ++mi)
                    acc[mi][nj] = __builtin_amdgcn_mfma_f32_16x16x32_f16(
                        af[mi], bu.v, acc[mi][nj], 0, 0, 0);
            }
        }

        if (g < 7) {                            // rotate prefetch buffers
#pragma unroll
            for (int kt = 0; kt < 4; ++kt)
#pragma unroll
                for (int nj = 0; nj < 2; ++nj) qc[kt][nj] = qn[kt][nj];
#pragma unroll
            for (int nj = 0; nj < 2; ++nj) { svc[nj] = svn[nj]; zwc[nj] = zwn[nj]; }
        }
    }

    // ---- epilogue: bf16 fragment-major partials, one 64B store/thread ----
    union { ushort u[32]; u16x8_t v8[4]; } ob;
#pragma unroll
    for (int mi = 0; mi < 4; ++mi)
#pragma unroll
        for (int nj = 0; nj < 2; ++nj)
#pragma unroll
            for (int j = 0; j < 4; ++j) {
                __hip_bfloat16 h = __float2bfloat16(acc[mi][nj][j]);
                ob.u[(mi * 2 + nj) * 4 + j] = *reinterpret_cast<ushort*>(&h);
            }
    u16x8_t* pb = (u16x8_t*)part + ((size_t)(ks * 32 + nt) * 512 + threadIdx.x) * 4;
#pragma unroll
    for (int i = 0; i < 4; ++i) pb[i] = ob.v8[i];
}

// ---------------------------------------------------------------------------
// Stage B: sum 8 bf16 K-split partials + bias -> out.
// 512 blocks x 256 thr (2x TLP vs before), u16x4 8B loads, 4 outputs/thr.
// ---------------------------------------------------------------------------
__global__ void __launch_bounds__(256)
wol_reduce(const ushort* __restrict__ part,
           const float*  __restrict__ bias,
           float* __restrict__ out) {
    const int u    = blockIdx.x * 256 + threadIdx.x;     // 131072 threads
    const int v4   = u & 7;              // which u16x4 of the thread's 32
    const int tidA = (u >> 3) & 511;     // stage-A thread id
    const int nt   = u >> 12;            // stage-A N-tile 0..31

    float s4[4] = {0.0f, 0.0f, 0.0f, 0.0f};
#pragma unroll
    for (int ks = 0; ks < KSPLIT; ++ks) {
        const u16x4_t p = *((const u16x4_t*)part +
                            (((size_t)(ks * 32 + nt) * 512 + tidA) * 8 + v4));
#pragma unroll
        for (int e = 0; e < 4; ++e) {
            union { unsigned b; float f; } cv;
            cv.b = ((unsigned)(ushort)p[e]) << 16;   // bf16 -> f32 exact
            s4[e] += cv.f;
        }
    }

    const int wid = tidA >> 6, lane = tidA & 63;
    const int ln = lane & 15, kb = lane >> 4;
#pragma unroll
    for (int e = 0; e < 4; ++e) {
        const int idx = v4 * 4 + e;                  // (mi*2+nj)*4 + j
        const int mi = idx >> 3, nj = (idx >> 2) & 1, j = idx & 3;
        const int row = mi * 16 + kb * 4 + j;
        const int col = nt * 256 + wid * 32 + nj * 16 + ln;
        out[(size_t)row * OUT_F + col] = s4[e] + bias[col];
    }
}

extern "C" void kernel_launch(void* const* d_in, const int* in_sizes, int n_in,
                              void* d_out, int out_size, void* d_ws, size_t ws_size,
                              hipStream_t stream) {
    const float* x    = (const float*)d_in[0];
    const int*   qw   = (const int*)d_in[1];
    const int*   qz   = (const int*)d_in[2];
    const float* sc   = (const float*)d_in[3];
    const float* bias = (const float*)d_in[4];
    float* out = (float*)d_out;

    ushort* prt = (ushort*)d_ws;                 // 8 MiB bf16 partials

    (void)in_sizes; (void)n_in; (void)ws_size; (void)out_size;

    wol_mfma<<<256, 512, 0, stream>>>(x, qw, qz, sc, prt);
    wol_reduce<<<512, 256, 0, stream>>>(prt, bias, out);
}